// Round 1
// 282.546 us; speedup vs baseline: 1.0223x; 1.0223x over previous
//
#include <hip/hip_runtime.h>
#include <hip/hip_bf16.h>
#include <stdint.h>

#define H_DIM 1024
#define S_DIM 4096
#define B_DIM 4
#define NTRI 36   // 8x8 tile grid, lower triangle incl. diagonal

typedef __bf16 bf16x8 __attribute__((ext_vector_type(8)));
typedef float f32x4 __attribute__((ext_vector_type(4)));
typedef unsigned short u16x4 __attribute__((ext_vector_type(4)));

__device__ __forceinline__ unsigned short f2bf(float f) {
    union { float f; uint32_t u; } v; v.f = f;
    uint32_t u = v.u;
    uint32_t r = (u + 0x7FFFu + ((u >> 16) & 1u)) >> 16;  // round-to-nearest-even
    return (unsigned short)r;
}
__device__ __forceinline__ float bf2f(unsigned short u) {
    union { uint32_t u; float f; } v; v.u = (uint32_t)u << 16; return v.f;
}

// Raw barrier with compiler memory fence (no vmcnt/lgkmcnt drain — that is the
// whole point; __syncthreads() would emit s_waitcnt vmcnt(0) first).
__device__ __forceinline__ void wg_barrier() {
    asm volatile("s_barrier" ::: "memory");
}

// X[b][s][h] fp32 -> Xb[b][s][h] bf16  and  XT[b][h][s] bf16
__global__ void cast_x_kernel(const float* __restrict__ X,
                              unsigned short* __restrict__ Xb,
                              unsigned short* __restrict__ XT) {
    __shared__ float tile[32][33];
    const int b  = blockIdx.z;
    const int h0 = blockIdx.x * 32;
    const int s0 = blockIdx.y * 32;
    const int tx = threadIdx.x;   // 0..31
    const int ty = threadIdx.y;   // 0..7
    const float* src = X + ((size_t)b * S_DIM + s0) * H_DIM + h0;
#pragma unroll
    for (int i = 0; i < 4; ++i) {
        int s = ty + 8 * i;
        float v = src[(size_t)s * H_DIM + tx];
        tile[s][tx] = v;
        Xb[((size_t)b * S_DIM + s0 + s) * H_DIM + h0 + tx] = f2bf(v);
    }
    __syncthreads();
#pragma unroll
    for (int i = 0; i < 4; ++i) {
        int hh = ty + 8 * i;
        XT[((size_t)b * H_DIM + h0 + hh) * S_DIM + s0 + tx] = f2bf(tile[tx][hh]);
    }
}

// W[o][h'] fp32 -> WT[h'][o] bf16
__global__ void cast_w_kernel(const float* __restrict__ W,
                              unsigned short* __restrict__ WT) {
    __shared__ float tile[32][33];
    const int b0 = blockIdx.x * 32;   // cols of W (h')
    const int o0 = blockIdx.y * 32;   // rows of W (o)
    const int tx = threadIdx.x;
    const int ty = threadIdx.y;
#pragma unroll
    for (int i = 0; i < 4; ++i) {
        int o = ty + 8 * i;
        tile[o][tx] = W[(size_t)(o0 + o) * H_DIM + b0 + tx];
    }
    __syncthreads();
#pragma unroll
    for (int i = 0; i < 4; ++i) {
        int bb = ty + 8 * i;
        WT[(size_t)(b0 + bb) * H_DIM + o0 + tx] = f2bf(tile[tx][bb]);
    }
}

// Sum NSPLIT bf16 partials -> bf16. Plain elementwise (for MT).
template <int NSPLIT>
__global__ void reduce_cast_u16_kernel(const unsigned short* __restrict__ P,
                                       unsigned short* __restrict__ Out,
                                       size_t sSplit) {
    size_t i = ((size_t)blockIdx.x * blockDim.x + threadIdx.x) * 4;
    float s0 = 0.f, s1 = 0.f, s2 = 0.f, s3 = 0.f;
#pragma unroll
    for (int sp = 0; sp < NSPLIT; ++sp) {
        u16x4 u = *(const u16x4*)&P[(size_t)sp * sSplit + i];
        s0 += bf2f(u[0]); s1 += bf2f(u[1]); s2 += bf2f(u[2]); s3 += bf2f(u[3]);
    }
    u16x4 o;
    o[0] = f2bf(s0); o[1] = f2bf(s1); o[2] = f2bf(s2); o[3] = f2bf(s3);
    *(u16x4*)&Out[i] = o;
}

// Symmetric reduce for G: sum NS bf16 partial tiles (lower-triangle list),
// write tile to G[ti][tj] and transpose to G[tj][ti] via LDS (pad 129).
// Diagonal tiles double-write bitwise-identical values (benign).
template <int NS>
__global__ __launch_bounds__(256)
void reduce_sym_kernel(const unsigned short* __restrict__ P,
                       unsigned short* __restrict__ G) {
    __shared__ unsigned short t[128 * 129];
    const int tid  = threadIdx.x;
    const int tile = blockIdx.x;
    const int b    = blockIdx.y;
    int ti = 0;
    while ((ti + 1) * (ti + 2) / 2 <= tile) ++ti;
    const int tj = tile - ti * (ti + 1) / 2;
    unsigned short* Gb = G + (size_t)b * (H_DIM * H_DIM);
    const unsigned short* Pb = P + ((size_t)(b * NS) * NTRI + tile) * 16384;
#pragma unroll
    for (int it = 0; it < 16; ++it) {
        int i = it * 1024 + tid * 4;
        float s0 = 0.f, s1 = 0.f, s2 = 0.f, s3 = 0.f;
#pragma unroll
        for (int sp = 0; sp < NS; ++sp) {
            u16x4 u = *(const u16x4*)&Pb[(size_t)sp * (NTRI * 16384) + i];
            s0 += bf2f(u[0]); s1 += bf2f(u[1]); s2 += bf2f(u[2]); s3 += bf2f(u[3]);
        }
        u16x4 o;
        o[0] = f2bf(s0); o[1] = f2bf(s1); o[2] = f2bf(s2); o[3] = f2bf(s3);
        int r = i >> 7, c = i & 127;
        *(u16x4*)&Gb[(size_t)(ti * 128 + r) * H_DIM + tj * 128 + c] = o;
        t[r * 129 + c + 0] = o[0];
        t[r * 129 + c + 1] = o[1];
        t[r * 129 + c + 2] = o[2];
        t[r * 129 + c + 3] = o[3];
    }
    __syncthreads();
#pragma unroll
    for (int it = 0; it < 16; ++it) {
        int j = it * 1024 + tid * 4;
        int rr = j >> 7, cc = j & 127;
        u16x4 o;
        o[0] = t[(cc + 0) * 129 + rr];
        o[1] = t[(cc + 1) * 129 + rr];
        o[2] = t[(cc + 2) * 129 + rr];
        o[3] = t[(cc + 3) * 129 + rr];
        *(u16x4*)&Gb[(size_t)(tj * 128 + rr) * H_DIM + ti * 128 + cc] = o;
    }
}

// C[M,N] = A[M,K] @ Bt[N,K]^T  (bf16 in, fp32 accum, OutT out)
// 128x128 tile, BK=64, 256 threads (4 waves), 4x4 frags of
// v_mfma_f32_16x16x32_bf16. LDS fragment-major [BK/8][128][8].
//
// R6 change — COUNTED-VMCNT K-loop (T4 from the technique catalog):
// The previous loop used __syncthreads() per iter, whose implicit
// s_waitcnt vmcnt(0) drained the JUST-ISSUED prefetch loads too (the
// measured m97-ceiling stall: MfmaUtil 16%, 75% idle). New schedule:
//   prologue: stage(tile0), stage(tile1)            // 16 loads in flight
//   iter t:   s_waitcnt vmcnt(8)   // tile t done, tile t+1 stays in flight
//             s_barrier            // raw — no drain
//             compute buf[t&1]
//             s_barrier            // readers of buf[t&1] done
//             stage(buf[t&1], tile t+2)
// Loads now have ~2 full iterations in flight; vmcnt never drains to 0
// in the main loop. LDS 64KB -> 2 blocks/CU (8 waves/CU interleave stalls).
// NSPLIT>1: blockIdx.z = bz*NSPLIT+sp, K/NSPLIT slice per block.
// TRI: blockIdx.x = lower-triangle tile index, tile-local output.
// SWAPXY: x = M-tile, y = N-tile (XCD swizzle; R5: FETCH 137->49 MB).
// Epilogue: per-wave LDS transpose, stride 68 floats (write phase 2-way).
template <typename OutT, int NSPLIT, bool TRI, bool SWAPXY>
__global__ __launch_bounds__(256, 2)
void gemm_bt_kernel(const unsigned short* __restrict__ A,
                    const unsigned short* __restrict__ Bt,
                    OutT* __restrict__ C,
                    int K, int lda, int ldb, int ldc,
                    size_t sA, size_t sB, size_t sC, size_t sSplit) {
    __shared__ __align__(16) union Sh {
        unsigned short stage[2][2][8192];   // [buf][A=0/B=1][frag-major tile]
        float epi[4][1088];                 // epilogue: 16 rows x stride 68 / wave
    } sh;

    const int tid  = threadIdx.x;
    const int w    = tid >> 6;
    const int lane = tid & 63;
    const int wm   = w & 1;
    const int wn   = w >> 1;
    const int q    = lane >> 4;    // 0..3
    const int col  = lane & 15;

    int tileM, tileN, tileIdx = 0;
    if constexpr (TRI) {
        tileIdx = (int)blockIdx.x;
        int ti = 0;
        while ((ti + 1) * (ti + 2) / 2 <= tileIdx) ++ti;
        int tj = tileIdx - ti * (ti + 1) / 2;
        tileM = ti * 128;
        tileN = tj * 128;
    } else if constexpr (SWAPXY) {
        tileM = blockIdx.x * 128;
        tileN = blockIdx.y * 128;
    } else {
        tileN = blockIdx.x * 128;
        tileM = blockIdx.y * 128;
    }
    const int bz   = blockIdx.z / NSPLIT;
    const int sp   = blockIdx.z % NSPLIT;
    const int Ksub = K / NSPLIT;

    const unsigned short* Ab = A + sA * bz + (size_t)sp * Ksub;
    const unsigned short* Bb = Bt + sB * bz + (size_t)sp * Ksub;

    const unsigned short* gA[4];
    const unsigned short* gB[4];
    int ldsOff[4];
#pragma unroll
    for (int i = 0; i < 4; ++i) {
        int chunk = (w << 2) | i;              // 0..15, uniform per wave
        int m  = ((chunk & 1) << 6) | lane;    // 0..127
        int k8 = chunk >> 1;                   // 0..7
        gA[i] = Ab + (size_t)(tileM + m) * lda + k8 * 8;
        gB[i] = Bb + (size_t)(tileN + m) * ldb + k8 * 8;
        ldsOff[i] = chunk * 512;
    }

    // stage one 128x64 A-tile + B-tile into buf; 8 loads/thread, advances ptrs
    auto stage = [&](int buf) {
#pragma unroll
        for (int i = 0; i < 4; ++i) {
            __builtin_amdgcn_global_load_lds(
                (const __attribute__((address_space(1))) void*)gA[i],
                (__attribute__((address_space(3))) void*)&sh.stage[buf][0][ldsOff[i]],
                16, 0, 0);
            __builtin_amdgcn_global_load_lds(
                (const __attribute__((address_space(1))) void*)gB[i],
                (__attribute__((address_space(3))) void*)&sh.stage[buf][1][ldsOff[i]],
                16, 0, 0);
            gA[i] += 64;
            gB[i] += 64;
        }
    };

    f32x4 acc[4][4];
#pragma unroll
    for (int r = 0; r < 4; ++r)
#pragma unroll
        for (int c = 0; c < 4; ++c)
            acc[r][c] = (f32x4){0.f, 0.f, 0.f, 0.f};

    const int T = Ksub >> 6;   // K-tiles of 64

    // prologue: two tiles in flight
    stage(0);
    if (T > 1) stage(1);

    for (int t = 0; t < T; ++t) {
        // tile t's 8 loads complete; tile t+1's 8 loads STAY IN FLIGHT
        if (t + 1 < T) asm volatile("s_waitcnt vmcnt(8)" ::: "memory");
        else           asm volatile("s_waitcnt vmcnt(0)" ::: "memory");
        wg_barrier();

        const int cur = t & 1;
        const unsigned short* As = sh.stage[cur][0];
        const unsigned short* Bs = sh.stage[cur][1];
#pragma unroll
        for (int kc = 0; kc < 2; ++kc) {       // kk = kc*32
            bf16x8 av[4], bv[4];
#pragma unroll
            for (int r = 0; r < 4; ++r)
                av[r] = *(const bf16x8*)&As[(((kc * 4 + q) * 128) + wm * 64 + r * 16 + col) * 8];
#pragma unroll
            for (int c = 0; c < 4; ++c)
                bv[c] = *(const bf16x8*)&Bs[(((kc * 4 + q) * 128) + wn * 64 + c * 16 + col) * 8];
#pragma unroll
            for (int r = 0; r < 4; ++r)
#pragma unroll
                for (int c = 0; c < 4; ++c)
                    acc[r][c] = __builtin_amdgcn_mfma_f32_16x16x32_bf16(
                        av[r], bv[c], acc[r][c], 0, 0, 0);
        }

        // all waves done reading buf[cur] before it is restaged
        wg_barrier();
        if (t + 2 < T) stage(cur);
    }

    OutT* Cb;
    int ldcl, rowBase, colBase;
    if constexpr (TRI) {
        Cb = C + ((size_t)blockIdx.z * NTRI + tileIdx) * 16384;
        ldcl = 128; rowBase = 0; colBase = 0;
    } else {
        Cb = C + sC * bz + sSplit * sp;
        ldcl = ldc; rowBase = tileM; colBase = tileN;
    }

    // vectorized epilogue: per-wave f32 slice (stride 68), phase-barriered
    float* lws = sh.epi[w];
    const int lr = lane >> 4;      // 0..3
    const int lc = lane & 15;      // 0..15
#pragma unroll
    for (int r = 0; r < 4; ++r) {
        __syncthreads();   // r=0: K-loop LDS reads done; r>0: prev read phase done
#pragma unroll
        for (int c = 0; c < 4; ++c)
#pragma unroll
            for (int v = 0; v < 4; ++v)
                lws[(q * 4 + v) * 68 + c * 16 + col] = acc[r][c][v];
        __syncthreads();   // write phase visible before read phase
#pragma unroll
        for (int p = 0; p < 4; ++p) {
            f32x4 t = *(const f32x4*)&lws[(p * 4 + lr) * 68 + lc * 4];
            int row  = rowBase + wm * 64 + r * 16 + p * 4 + lr;
            int colg = colBase + wn * 64 + lc * 4;
            if constexpr (sizeof(OutT) == 2) {
                u16x4 u;
                u[0] = f2bf(t[0]); u[1] = f2bf(t[1]);
                u[2] = f2bf(t[2]); u[3] = f2bf(t[3]);
                *(u16x4*)&Cb[(size_t)row * ldcl + colg] = u;
            } else {
                *(f32x4*)&Cb[(size_t)row * ldcl + colg] = t;
            }
        }
    }
}

extern "C" void kernel_launch(void* const* d_in, const int* in_sizes, int n_in,
                              void* d_out, int out_size, void* d_ws, size_t ws_size,
                              hipStream_t stream) {
    const float* X = (const float*)d_in[0];   // [4,4096,1024]
    const float* W = (const float*)d_in[1];   // [1024,1024]
    float* out = (float*)d_out;               // [4,4096,1024] fp32

    char* ws = (char*)d_ws;
    unsigned short* Xb = (unsigned short*)(ws);              // 33,554,432  [b][s][h]
    unsigned short* XT = (unsigned short*)(ws + 33554432);   // 33,554,432  [b][h][s]
    unsigned short* WT = (unsigned short*)(ws + 67108864);   //  2,097,152  [h'][o]
    unsigned short* G  = (unsigned short*)(ws + 69206016);   //  8,388,608  [b][o][h]
    unsigned short* MT = (unsigned short*)(ws + 77594624);   //  8,388,608  [b][h''][h]
    // Scratch region (reused serially): G partials then MT partials.
    unsigned short* Gpart  = (unsigned short*)(ws + 85983232); // 16*36*16384*2 = 18,874,368
    unsigned short* MTpart = (unsigned short*)(ws + 85983232); // 2*4*1M*2      = 16,777,216
    // high-water: 104,857,600 bytes < 153,092,096 proven available (R3)

    // 1) casts + transposes
    cast_x_kernel<<<dim3(H_DIM / 32, S_DIM / 32, B_DIM), dim3(32, 8), 0, stream>>>(X, Xb, XT);
    cast_w_kernel<<<dim3(H_DIM / 32, H_DIM / 32, 1), dim3(32, 8), 0, stream>>>(W, WT);

    // 2) G_b = XT_b @ XT_b^T, symmetric: 36 lower-tri tiles, split-K=4 (Ksub=1024,
    //    16 iters), bf16 partials. 576 blocks ~ 2.25/CU (LDS limit is 2).
    gemm_bt_kernel<unsigned short, 4, true, false><<<dim3(NTRI, 1, B_DIM * 4), 256, 0, stream>>>(
        XT, XT, Gpart, S_DIM, S_DIM, S_DIM, 128,
        (size_t)H_DIM * S_DIM, (size_t)H_DIM * S_DIM, 0, 0);
    // 2b) reduce partials + mirror transpose -> bf16 G (full)
    reduce_sym_kernel<4><<<dim3(NTRI, B_DIM), 256, 0, stream>>>(Gpart, G);

    // 3) MT_b = G_b @ WT^T (= G W, G symmetric), split-K=2 (Ksub=512, 8 iters)
    gemm_bt_kernel<unsigned short, 2, false, false><<<dim3(8, 8, B_DIM * 2), 256, 0, stream>>>(
        G, WT, MTpart, H_DIM, H_DIM, H_DIM, H_DIM,
        (size_t)H_DIM * H_DIM, (size_t)0, (size_t)H_DIM * H_DIM,
        (size_t)B_DIM * H_DIM * H_DIM);
    reduce_cast_u16_kernel<2><<<dim3(B_DIM * H_DIM * H_DIM / 4 / 256), 256, 0, stream>>>(
        MTpart, MT, (size_t)B_DIM * H_DIM * H_DIM);

    // 4) att_b = Xb_b @ MT_b^T   [4096 x 1024], K = 1024 (16 iters), fp32 out
    //    SWAPXY: x = M-tile (32), y = N-tile (8) -> A-tile sharers same XCD.
    gemm_bt_kernel<float, 1, false, true><<<dim3(S_DIM / 128, 8, B_DIM), 256, 0, stream>>>(
        Xb, MT, out, H_DIM, H_DIM, H_DIM, H_DIM,
        (size_t)S_DIM * H_DIM, (size_t)H_DIM * H_DIM, (size_t)S_DIM * H_DIM, 0);
}

// Round 2
// 264.559 us; speedup vs baseline: 1.0918x; 1.0680x over previous
//
#include <hip/hip_runtime.h>
#include <hip/hip_bf16.h>
#include <stdint.h>

#define H_DIM 1024
#define S_DIM 4096
#define B_DIM 4

typedef __bf16 bf16x8 __attribute__((ext_vector_type(8)));
typedef float f32x4 __attribute__((ext_vector_type(4)));
typedef unsigned short u16x4 __attribute__((ext_vector_type(4)));

__device__ __forceinline__ unsigned short f2bf(float f) {
    union { float f; uint32_t u; } v; v.f = f;
    uint32_t u = v.u;
    uint32_t r = (u + 0x7FFFu + ((u >> 16) & 1u)) >> 16;  // round-to-nearest-even
    return (unsigned short)r;
}
__device__ __forceinline__ float bf2f(unsigned short u) {
    union { uint32_t u; float f; } v; v.u = (uint32_t)u << 16; return v.f;
}

// Raw barrier (no implicit vmcnt/lgkmcnt drain — that is the whole point).
__device__ __forceinline__ void wg_barrier() {
    asm volatile("s_barrier" ::: "memory");
}

// Inline-asm LDS read: opaque to the compiler's LDS-DMA alias tracking, so it
// CANNOT insert its own s_waitcnt vmcnt(0) before it (the R1-diagnosed drain).
// Correctness is restored manually: lgkmcnt(0) + sched_barrier(0) before MFMA.
template <int IMM>
__device__ __forceinline__ bf16x8 ds_read_b128_imm(unsigned addr) {
    bf16x8 r;
    asm volatile("ds_read_b128 %0, %1 offset:%2"
                 : "=v"(r) : "v"(addr), "i"(IMM));
    return r;
}

// X[b][s][h] fp32 -> Xb[b][s][h] bf16  and  XT[b][h][s] bf16
__global__ void cast_x_kernel(const float* __restrict__ X,
                              unsigned short* __restrict__ Xb,
                              unsigned short* __restrict__ XT) {
    __shared__ float tile[32][33];
    const int b  = blockIdx.z;
    const int h0 = blockIdx.x * 32;
    const int s0 = blockIdx.y * 32;
    const int tx = threadIdx.x;   // 0..31
    const int ty = threadIdx.y;   // 0..7
    const float* src = X + ((size_t)b * S_DIM + s0) * H_DIM + h0;
#pragma unroll
    for (int i = 0; i < 4; ++i) {
        int s = ty + 8 * i;
        float v = src[(size_t)s * H_DIM + tx];
        tile[s][tx] = v;
        Xb[((size_t)b * S_DIM + s0 + s) * H_DIM + h0 + tx] = f2bf(v);
    }
    __syncthreads();
#pragma unroll
    for (int i = 0; i < 4; ++i) {
        int hh = ty + 8 * i;
        XT[((size_t)b * H_DIM + h0 + hh) * S_DIM + s0 + tx] = f2bf(tile[tx][hh]);
    }
}

// W[o][h'] fp32 -> WT[h'][o] bf16
__global__ void cast_w_kernel(const float* __restrict__ W,
                              unsigned short* __restrict__ WT) {
    __shared__ float tile[32][33];
    const int b0 = blockIdx.x * 32;   // cols of W (h')
    const int o0 = blockIdx.y * 32;   // rows of W (o)
    const int tx = threadIdx.x;
    const int ty = threadIdx.y;
#pragma unroll
    for (int i = 0; i < 4; ++i) {
        int o = ty + 8 * i;
        tile[o][tx] = W[(size_t)(o0 + o) * H_DIM + b0 + tx];
    }
    __syncthreads();
#pragma unroll
    for (int i = 0; i < 4; ++i) {
        int bb = ty + 8 * i;
        WT[(size_t)(b0 + bb) * H_DIM + o0 + tx] = f2bf(tile[tx][bb]);
    }
}

// Sum NSPLIT bf16 partials -> bf16. Plain elementwise.
template <int NSPLIT>
__global__ void reduce_cast_u16_kernel(const unsigned short* __restrict__ P,
                                       unsigned short* __restrict__ Out,
                                       size_t sSplit) {
    size_t i = ((size_t)blockIdx.x * blockDim.x + threadIdx.x) * 4;
    float s0 = 0.f, s1 = 0.f, s2 = 0.f, s3 = 0.f;
#pragma unroll
    for (int sp = 0; sp < NSPLIT; ++sp) {
        u16x4 u = *(const u16x4*)&P[(size_t)sp * sSplit + i];
        s0 += bf2f(u[0]); s1 += bf2f(u[1]); s2 += bf2f(u[2]); s3 += bf2f(u[3]);
    }
    u16x4 o;
    o[0] = f2bf(s0); o[1] = f2bf(s1); o[2] = f2bf(s2); o[3] = f2bf(s3);
    *(u16x4*)&Out[i] = o;
}

// ============================================================================
// R2: 8-phase deep-pipelined GEMM (T3+T4+T5 from the technique catalog).
// C[M,N] = A[M,K] @ Bt[N,K]^T  (bf16 in, fp32 accum, OutT out)
//
// Geometry: 256x256 tile, 512 threads = 8 waves (2M x 4N), per-wave C 128x64
// = 8x4 frags of v_mfma_f32_16x16x32_bf16 (acc 128 VGPR).
// K-tile = 32 (one MFMA k-step). LDS: FOUR K-tile buffers x (A 16KB + B 16KB)
// = 128 KB, fragment-major [k8(4)][row(256)][8] per operand (conflict-free
// ds_read_b128 AND legal linear global_load_lds dest — no swizzle needed).
//
// Pipeline: while computing tile n (2 phases), stage tile n+3 into buffer
// (n+3)&3 — that buffer's last reads were tile n-1, >=2 barriers earlier.
// Prefetch distance = 6 phases (~1200+ cyc, covers HBM latency), vs R1's 1
// iteration. vmcnt gates count loads (4/thread/tile): steady-state vmcnt(8),
// drain 4 -> 0 only in the last two tiles. ds_reads are inline asm so the
// compiler cannot re-insert vmcnt(0) drains (R1 failure mode); per-phase
// {s_barrier; lgkmcnt(0); sched_barrier(0); setprio(1); 16 MFMA; setprio(0);
// s_barrier} is the m201-proven convoy that makes setprio pay (T5).
// Requires T = Ksub/32 >= 4 and M,N multiples of 256.
// ============================================================================
template <typename OutT, int NSPLIT>
__global__ __launch_bounds__(512, 2)
void gemm_q4_kernel(const unsigned short* __restrict__ A,
                    const unsigned short* __restrict__ Bt,
                    OutT* __restrict__ C,
                    int K, int lda, int ldb, int ldc,
                    size_t sA, size_t sB, size_t sC, size_t sSplit) {
    extern __shared__ char smem_raw[];
    // stage region: [buf(4)][op(2)][8192 shorts] = 131072 B
    // epi region (after K-loop, post-__syncthreads): float[8][1088] = 34816 B

    const int tid  = threadIdx.x;
    const int w    = tid >> 6;       // 0..7
    const int lane = tid & 63;
    const int wm   = w & 1;          // M half: rows wm*128
    const int wn   = w >> 1;         // N quarter: cols wn*64
    const int q    = lane >> 4;      // 0..3
    const int col  = lane & 15;

    const int tileM = blockIdx.x * 256;
    const int tileN = blockIdx.y * 256;
    const int bz   = blockIdx.z / NSPLIT;
    const int sp   = blockIdx.z % NSPLIT;
    const int Ksub = K / NSPLIT;
    const int T    = Ksub >> 5;      // K-tiles of 32 (>= 4)

    const unsigned short* Ab = A + sA * bz + (size_t)sp * Ksub;
    const unsigned short* Bb = Bt + sB * bz + (size_t)sp * Ksub;

    auto lds3 = (__attribute__((address_space(3))) char*)&smem_raw[0];
    const unsigned ldsBase = (unsigned)(size_t)lds3;

    // fragment read bases (buf 0): A byte = q*4096 + (wm*128 + mf*16 + col)*16
    const unsigned aBase = ldsBase + (unsigned)(q * 4096 + wm * 2048 + col * 16);
    const unsigned bBase = ldsBase + 16384u + (unsigned)(q * 4096 + wn * 1024 + col * 16);

    // staging: chunk c = 2w+j covers k8l = c>>2 (k-cols), rows (c&3)*64..+63;
    // LDS dst is wave-uniform (HW appends lane*16 = consecutive rows).
    const unsigned short* srcA[2];
    const unsigned short* srcB[2];
    int dstOf[2];
#pragma unroll
    for (int j = 0; j < 2; ++j) {
        int c = 2 * w + j;
        int k8l = c >> 2, r64 = c & 3;
        srcA[j] = Ab + (size_t)(tileM + r64 * 64 + lane) * lda + k8l * 8;
        srcB[j] = Bb + (size_t)(tileN + r64 * 64 + lane) * ldb + k8l * 8;
        dstOf[j] = (k8l * 256 + r64 * 64) * 16;
    }

    auto stageA = [&](int buf) {
#pragma unroll
        for (int j = 0; j < 2; ++j) {
            __builtin_amdgcn_global_load_lds(
                (const __attribute__((address_space(1))) void*)srcA[j],
                (__attribute__((address_space(3))) void*)(lds3 + buf * 32768 + dstOf[j]),
                16, 0, 0);
            srcA[j] += 32;
        }
    };
    auto stageB = [&](int buf) {
#pragma unroll
        for (int j = 0; j < 2; ++j) {
            __builtin_amdgcn_global_load_lds(
                (const __attribute__((address_space(1))) void*)srcB[j],
                (__attribute__((address_space(3))) void*)(lds3 + buf * 32768 + 16384 + dstOf[j]),
                16, 0, 0);
            srcB[j] += 32;
        }
    };

    f32x4 acc[8][4];
#pragma unroll
    for (int r = 0; r < 8; ++r)
#pragma unroll
        for (int c = 0; c < 4; ++c)
            acc[r][c] = (f32x4){0.f, 0.f, 0.f, 0.f};

    // prologue: tiles 0,1,2 into bufs 0,1,2 (12 loads/thread, issue order
    // T0.A,T0.B,T1.A,T1.B,T2.A,T2.B) -> wait T0 (oldest 4) only.
    stageA(0); stageB(0);
    stageA(1); stageB(1);
    stageA(2); stageB(2);
    asm volatile("s_waitcnt vmcnt(8)" ::: "memory");
    wg_barrier();

    for (int n = 0; n < T; ++n) {
        const unsigned aAddr = aBase + (unsigned)((n & 3) << 15);
        const unsigned bAddr = bBase + (unsigned)((n & 3) << 15);
        const int nbuf = (n + 3) & 3;
        bf16x8 av[4], bv[4];

        // ---- phase 0: mf 0..3 x nf 0..3 ----
        av[0] = ds_read_b128_imm<0>(aAddr);
        av[1] = ds_read_b128_imm<256>(aAddr);
        av[2] = ds_read_b128_imm<512>(aAddr);
        av[3] = ds_read_b128_imm<768>(aAddr);
        bv[0] = ds_read_b128_imm<0>(bAddr);
        bv[1] = ds_read_b128_imm<256>(bAddr);
        bv[2] = ds_read_b128_imm<512>(bAddr);
        bv[3] = ds_read_b128_imm<768>(bAddr);
        if (n + 3 < T) stageA(nbuf);
        wg_barrier();
        asm volatile("s_waitcnt lgkmcnt(0)" ::: "memory");
        __builtin_amdgcn_sched_barrier(0);
        __builtin_amdgcn_s_setprio(1);
#pragma unroll
        for (int mf = 0; mf < 4; ++mf)
#pragma unroll
            for (int nf = 0; nf < 4; ++nf)
                acc[mf][nf] = __builtin_amdgcn_mfma_f32_16x16x32_bf16(
                    av[mf], bv[nf], acc[mf][nf], 0, 0, 0);
        __builtin_amdgcn_s_setprio(0);
        wg_barrier();

        // ---- phase 1: mf 4..7, reuse bv ----
        av[0] = ds_read_b128_imm<1024>(aAddr);
        av[1] = ds_read_b128_imm<1280>(aAddr);
        av[2] = ds_read_b128_imm<1536>(aAddr);
        av[3] = ds_read_b128_imm<1792>(aAddr);
        if (n + 3 < T) stageB(nbuf);
        // gate for tile n+1 (staged 2 tiles ago): leave tiles n+2,n+3 in flight
        if (n < T - 3)       asm volatile("s_waitcnt vmcnt(8)" ::: "memory");
        else if (n == T - 3) asm volatile("s_waitcnt vmcnt(4)" ::: "memory");
        else                 asm volatile("s_waitcnt vmcnt(0)" ::: "memory");
        wg_barrier();
        asm volatile("s_waitcnt lgkmcnt(0)" ::: "memory");
        __builtin_amdgcn_sched_barrier(0);
        __builtin_amdgcn_s_setprio(1);
#pragma unroll
        for (int mf = 0; mf < 4; ++mf)
#pragma unroll
            for (int nf = 0; nf < 4; ++nf)
                acc[4 + mf][nf] = __builtin_amdgcn_mfma_f32_16x16x32_bf16(
                    av[mf], bv[nf], acc[4 + mf][nf], 0, 0, 0);
        __builtin_amdgcn_s_setprio(0);
        wg_barrier();
    }

    // epilogue: per-wave LDS transpose (stride 68 floats), coalesced stores.
    OutT* Cb = C + sC * bz + sSplit * sp;
    __syncthreads();   // all waves done with stage region before epi overlay
    float* lws = (float*)(smem_raw) + (size_t)w * 1088;
    const int lr = lane >> 4;
    const int lc = lane & 15;
#pragma unroll
    for (int mf = 0; mf < 8; ++mf) {
#pragma unroll
        for (int nf = 0; nf < 4; ++nf)
#pragma unroll
            for (int v = 0; v < 4; ++v)
                lws[(q * 4 + v) * 68 + nf * 16 + col] = acc[mf][nf][v];
#pragma unroll
        for (int p = 0; p < 4; ++p) {
            f32x4 t = *(const f32x4*)&lws[(p * 4 + lr) * 68 + lc * 4];
            int row  = tileM + wm * 128 + mf * 16 + p * 4 + lr;
            int colg = tileN + wn * 64 + lc * 4;
            if constexpr (sizeof(OutT) == 2) {
                u16x4 u;
                u[0] = f2bf(t[0]); u[1] = f2bf(t[1]);
                u[2] = f2bf(t[2]); u[3] = f2bf(t[3]);
                *(u16x4*)&Cb[(size_t)row * ldc + colg] = u;
            } else {
                *(f32x4*)&Cb[(size_t)row * ldc + colg] = t;
            }
        }
    }
}

extern "C" void kernel_launch(void* const* d_in, const int* in_sizes, int n_in,
                              void* d_out, int out_size, void* d_ws, size_t ws_size,
                              hipStream_t stream) {
    const float* X = (const float*)d_in[0];   // [4,4096,1024]
    const float* W = (const float*)d_in[1];   // [1024,1024]
    float* out = (float*)d_out;               // [4,4096,1024] fp32

    char* ws = (char*)d_ws;
    unsigned short* Xb = (unsigned short*)(ws);              // 33,554,432  [b][s][h]
    unsigned short* XT = (unsigned short*)(ws + 33554432);   // 33,554,432  [b][h][s]
    unsigned short* WT = (unsigned short*)(ws + 67108864);   //  2,097,152  [h'][o]
    unsigned short* G  = (unsigned short*)(ws + 69206016);   //  8,388,608  [b][o][h]
    unsigned short* MT = (unsigned short*)(ws + 77594624);   //  8,388,608  [b][h''][h]
    // Scratch (reused serially): Gpart then MTpart, each [sp(4)][b][1024][1024]
    unsigned short* Gpart  = (unsigned short*)(ws + 85983232); // 16,777,216
    unsigned short* MTpart = (unsigned short*)(ws + 85983232); // 16,777,216
    // high-water: 102,760,448 bytes < 153,092,096 proven available

    const size_t sBH = (size_t)B_DIM * H_DIM * H_DIM;

    // 1) casts + transposes
    cast_x_kernel<<<dim3(H_DIM / 32, S_DIM / 32, B_DIM), dim3(32, 8), 0, stream>>>(X, Xb, XT);
    cast_w_kernel<<<dim3(H_DIM / 32, H_DIM / 32, 1), dim3(32, 8), 0, stream>>>(W, WT);

    // 2) G_b = XT_b @ XT_b^T, FULL (both triangles: perfectly balanced 256
    //    blocks, kills reduce_sym; symmetric halves are bitwise-identical).
    //    split-K=4 (Ksub=1024, T=32), bf16 partials -> reduce.
    gemm_q4_kernel<unsigned short, 4><<<dim3(4, 4, B_DIM * 4), 512, 131072, stream>>>(
        XT, XT, Gpart, S_DIM, S_DIM, S_DIM, H_DIM,
        (size_t)H_DIM * S_DIM, (size_t)H_DIM * S_DIM, (size_t)H_DIM * H_DIM, sBH);
    reduce_cast_u16_kernel<4><<<dim3(sBH / 4 / 256), 256, 0, stream>>>(Gpart, G, sBH);

    // 3) MT_b = G_b @ WT^T, split-K=4 (Ksub=256, T=8)
    gemm_q4_kernel<unsigned short, 4><<<dim3(4, 4, B_DIM * 4), 512, 131072, stream>>>(
        G, WT, MTpart, H_DIM, H_DIM, H_DIM, H_DIM,
        (size_t)H_DIM * H_DIM, (size_t)0, (size_t)H_DIM * H_DIM, sBH);
    reduce_cast_u16_kernel<4><<<dim3(sBH / 4 / 256), 256, 0, stream>>>(MTpart, MT, sBH);

    // 4) att_b = Xb_b @ MT_b^T  [4096x1024], K=1024 (T=32), fp32 out.
    //    grid (16,4,4) = 256 blocks = 1/CU exactly.
    gemm_q4_kernel<float, 1><<<dim3(S_DIM / 256, H_DIM / 256, B_DIM), 512, 131072, stream>>>(
        Xb, MT, out, H_DIM, H_DIM, H_DIM, H_DIM,
        (size_t)S_DIM * H_DIM, (size_t)H_DIM * H_DIM, (size_t)S_DIM * H_DIM, 0);
}

// Round 3
// 262.320 us; speedup vs baseline: 1.1011x; 1.0085x over previous
//
#include <hip/hip_runtime.h>
#include <hip/hip_bf16.h>
#include <stdint.h>

#define H_DIM 1024
#define S_DIM 4096
#define B_DIM 4

typedef __bf16 bf16x8 __attribute__((ext_vector_type(8)));
typedef float f32x4 __attribute__((ext_vector_type(4)));
typedef unsigned short u16x4 __attribute__((ext_vector_type(4)));
typedef unsigned short u16x8 __attribute__((ext_vector_type(8)));

__device__ __forceinline__ unsigned short f2bf(float f) {
    union { float f; uint32_t u; } v; v.f = f;
    uint32_t u = v.u;
    uint32_t r = (u + 0x7FFFu + ((u >> 16) & 1u)) >> 16;  // round-to-nearest-even
    return (unsigned short)r;
}
__device__ __forceinline__ float bf2f(unsigned short u) {
    union { uint32_t u; float f; } v; v.u = (uint32_t)u << 16; return v.f;
}

// Raw barrier (no implicit vmcnt/lgkmcnt drain).
__device__ __forceinline__ void wg_barrier() {
    asm volatile("s_barrier" ::: "memory");
}

// Inline-asm LDS read: opaque to the compiler's LDS-DMA alias tracking, so it
// cannot insert its own s_waitcnt vmcnt(0) before it. Correctness restored
// manually: counted lgkmcnt + sched_barrier(0) before the dependent MFMAs.
template <int IMM>
__device__ __forceinline__ bf16x8 ds_read_b128_imm(unsigned addr) {
    bf16x8 r;
    asm volatile("ds_read_b128 %0, %1 offset:%2"
                 : "=v"(r) : "v"(addr), "i"(IMM));
    return r;
}

// X[b][s][h] fp32 -> Xb[b][s][h] bf16  and  XT[b][h][s] bf16
// R3: fully vectorized (float4 in, u16x4 out both streams; R2 wrote 64 MB of
// bf16 as scalar u16 stores). 64x64 tile, 256 threads, LDS f32 [64][65]
// (scalar LDS ops, 2-way bank pattern = free; global side is the BW that counts).
__global__ __launch_bounds__(256)
void cast_x_kernel(const float* __restrict__ X,
                   unsigned short* __restrict__ Xb,
                   unsigned short* __restrict__ XT) {
    __shared__ float tile[64][65];
    const int b  = blockIdx.z;
    const int h0 = blockIdx.x * 64;
    const int s0 = blockIdx.y * 64;
    const int tx = threadIdx.x;   // 0..15
    const int ty = threadIdx.y;   // 0..15
#pragma unroll
    for (int j = 0; j < 4; ++j) {
        int s = ty + 16 * j;
        f32x4 v = *(const f32x4*)&X[((size_t)b * S_DIM + s0 + s) * H_DIM + h0 + tx * 4];
        u16x4 o;
#pragma unroll
        for (int k = 0; k < 4; ++k) {
            tile[s][tx * 4 + k] = v[k];
            o[k] = f2bf(v[k]);
        }
        *(u16x4*)&Xb[((size_t)b * S_DIM + s0 + s) * H_DIM + h0 + tx * 4] = o;
    }
    __syncthreads();
#pragma unroll
    for (int j = 0; j < 4; ++j) {
        int hh = ty + 16 * j;
        u16x4 o;
#pragma unroll
        for (int k = 0; k < 4; ++k)
            o[k] = f2bf(tile[tx * 4 + k][hh]);
        *(u16x4*)&XT[((size_t)b * H_DIM + h0 + hh) * S_DIM + s0 + tx * 4] = o;
    }
}

// W[o][h'] fp32 -> WT[h'][o] bf16 (small: 4 MB read; leave simple)
__global__ void cast_w_kernel(const float* __restrict__ W,
                              unsigned short* __restrict__ WT) {
    __shared__ float tile[32][33];
    const int b0 = blockIdx.x * 32;   // cols of W (h')
    const int o0 = blockIdx.y * 32;   // rows of W (o)
    const int tx = threadIdx.x;
    const int ty = threadIdx.y;
#pragma unroll
    for (int i = 0; i < 4; ++i) {
        int o = ty + 8 * i;
        tile[o][tx] = W[(size_t)(o0 + o) * H_DIM + b0 + tx];
    }
    __syncthreads();
#pragma unroll
    for (int i = 0; i < 4; ++i) {
        int bb = ty + 8 * i;
        WT[(size_t)(b0 + bb) * H_DIM + o0 + tx] = f2bf(tile[tx][bb]);
    }
}

// Sum NSPLIT bf16 partials -> bf16. 16B/lane both directions (R3 widened).
template <int NSPLIT>
__global__ void reduce_cast_u16_kernel(const unsigned short* __restrict__ P,
                                       unsigned short* __restrict__ Out,
                                       size_t sSplit) {
    size_t i = ((size_t)blockIdx.x * blockDim.x + threadIdx.x) * 8;
    float s[8] = {0.f, 0.f, 0.f, 0.f, 0.f, 0.f, 0.f, 0.f};
#pragma unroll
    for (int sp = 0; sp < NSPLIT; ++sp) {
        u16x8 u = *(const u16x8*)&P[(size_t)sp * sSplit + i];
#pragma unroll
        for (int k = 0; k < 8; ++k) s[k] += bf2f(u[k]);
    }
    u16x8 o;
#pragma unroll
    for (int k = 0; k < 8; ++k) o[k] = f2bf(s[k]);
    *(u16x8*)&Out[i] = o;
}

// ============================================================================
// R3: relaxed-sync deep-pipelined GEMM.
// C[M,N] = A[M,K] @ Bt[N,K]^T  (bf16 in, fp32 accum, OutT out)
//
// Geometry: 256x256 tile, 512 threads = 8 waves (2M x 4N), per-wave C 128x64
// = 8x4 frags of v_mfma_f32_16x16x32_bf16. K-tile = 32. LDS: FOUR K-tile
// buffers x (A 16KB + B 16KB) = 128 KB, fragment-major [k8(4)][row(256)][8]
// (conflict-free ds_read_b128 AND legal linear global_load_lds dest).
//
// R2 post-mortem: the 4-barriers-per-tile convoy serialized the block-wide
// LDS-read drain (~1150 cyc/tile) against the MFMA cluster (~1240 cyc/tile)
// -> 22% MfmaUtil. R3 keeps ONE barrier per K-tile (the correctness-minimal
// set) and makes all read->MFMA waits WAVE-LOCAL counted lgkmcnt, so waves
// drift and one wave's ds_reads overlap another's MFMAs (cross-wave
// LDS/matrix pipe overlap, m114 mechanism).
//
// Correctness argument (1 barrier/tile):
//  - tile n data: each wave gates its OWN dma (vmcnt(8): tiles n+1,n+2 stay in
//    flight) BEFORE the barrier; after the barrier everyone's tile-n loads
//    are in LDS.
//  - restage of buf((n+3)&3) happens after the tile-n barrier; its previous
//    reader was tile n-1, and every wave's tile-(n-1) reads completed (data
//    returned) before its own lgkmcnt(0)+MFMA, which precede its barrier
//    arrival. No wave can still be reading it.
//  - wave drift is bounded to the current tile body by the barrier.
// Requires T = Ksub/32 >= 4 and M,N multiples of 256.
// ============================================================================
template <typename OutT, int NSPLIT>
__global__ __launch_bounds__(512, 2)
void gemm_q4_kernel(const unsigned short* __restrict__ A,
                    const unsigned short* __restrict__ Bt,
                    OutT* __restrict__ C,
                    int K, int lda, int ldb, int ldc,
                    size_t sA, size_t sB, size_t sC, size_t sSplit) {
    extern __shared__ char smem_raw[];
    // stage region: [buf(4)][op(2)][8192 shorts] = 131072 B
    // epi region (after K-loop, post-__syncthreads): float[8][1088] = 34816 B

    const int tid  = threadIdx.x;
    const int w    = tid >> 6;       // 0..7
    const int lane = tid & 63;
    const int wm   = w & 1;          // M half: rows wm*128
    const int wn   = w >> 1;         // N quarter: cols wn*64
    const int q    = lane >> 4;      // 0..3
    const int col  = lane & 15;

    const int tileM = blockIdx.x * 256;
    const int tileN = blockIdx.y * 256;
    const int bz   = blockIdx.z / NSPLIT;
    const int sp   = blockIdx.z % NSPLIT;
    const int Ksub = K / NSPLIT;
    const int T    = Ksub >> 5;      // K-tiles of 32 (>= 4)

    const unsigned short* Ab = A + sA * bz + (size_t)sp * Ksub;
    const unsigned short* Bb = Bt + sB * bz + (size_t)sp * Ksub;

    auto lds3 = (__attribute__((address_space(3))) char*)&smem_raw[0];
    const unsigned ldsBase = (unsigned)(size_t)lds3;

    // fragment read bases (buf 0): A byte = q*4096 + (wm*128 + mf*16 + col)*16
    const unsigned aBase = ldsBase + (unsigned)(q * 4096 + wm * 2048 + col * 16);
    const unsigned bBase = ldsBase + 16384u + (unsigned)(q * 4096 + wn * 1024 + col * 16);

    // staging: chunk c = 2w+j covers k8l = c>>2 (k-cols), rows (c&3)*64..+63;
    // LDS dst is wave-uniform (HW appends lane*16 = consecutive rows).
    const unsigned short* srcA[2];
    const unsigned short* srcB[2];
    int dstOf[2];
#pragma unroll
    for (int j = 0; j < 2; ++j) {
        int c = 2 * w + j;
        int k8l = c >> 2, r64 = c & 3;
        srcA[j] = Ab + (size_t)(tileM + r64 * 64 + lane) * lda + k8l * 8;
        srcB[j] = Bb + (size_t)(tileN + r64 * 64 + lane) * ldb + k8l * 8;
        dstOf[j] = (k8l * 256 + r64 * 64) * 16;
    }

    auto stageA = [&](int buf) {
#pragma unroll
        for (int j = 0; j < 2; ++j) {
            __builtin_amdgcn_global_load_lds(
                (const __attribute__((address_space(1))) void*)srcA[j],
                (__attribute__((address_space(3))) void*)(lds3 + buf * 32768 + dstOf[j]),
                16, 0, 0);
            srcA[j] += 32;
        }
    };
    auto stageB = [&](int buf) {
#pragma unroll
        for (int j = 0; j < 2; ++j) {
            __builtin_amdgcn_global_load_lds(
                (const __attribute__((address_space(1))) void*)srcB[j],
                (__attribute__((address_space(3))) void*)(lds3 + buf * 32768 + 16384 + dstOf[j]),
                16, 0, 0);
            srcB[j] += 32;
        }
    };

    f32x4 acc[8][4];
#pragma unroll
    for (int r = 0; r < 8; ++r)
#pragma unroll
        for (int c = 0; c < 4; ++c)
            acc[r][c] = (f32x4){0.f, 0.f, 0.f, 0.f};

    // prologue: tiles 0,1,2 into bufs 0,1,2 (12 loads/thread)
    stageA(0); stageB(0);
    stageA(1); stageB(1);
    stageA(2); stageB(2);

    for (int n = 0; n < T; ++n) {
        // own loads for tile n done; tiles n+1, n+2 (8 loads) stay in flight
        if (n <= T - 3)      asm volatile("s_waitcnt vmcnt(8)" ::: "memory");
        else if (n == T - 2) asm volatile("s_waitcnt vmcnt(4)" ::: "memory");
        else                 asm volatile("s_waitcnt vmcnt(0)" ::: "memory");
        wg_barrier();   // the ONLY barrier per tile

        if (n + 3 < T) { stageA((n + 3) & 3); stageB((n + 3) & 3); }

        const unsigned aAddr = aBase + (unsigned)((n & 3) << 15);
        const unsigned bAddr = bBase + (unsigned)((n & 3) << 15);
        bf16x8 av[8], bv[4];

        // issue ALL 12 reads up front (order matters for counted lgkmcnt):
        av[0] = ds_read_b128_imm<0>(aAddr);
        av[1] = ds_read_b128_imm<256>(aAddr);
        av[2] = ds_read_b128_imm<512>(aAddr);
        av[3] = ds_read_b128_imm<768>(aAddr);
        bv[0] = ds_read_b128_imm<0>(bAddr);
        bv[1] = ds_read_b128_imm<256>(bAddr);
        bv[2] = ds_read_b128_imm<512>(bAddr);
        bv[3] = ds_read_b128_imm<768>(bAddr);
        av[4] = ds_read_b128_imm<1024>(aAddr);
        av[5] = ds_read_b128_imm<1280>(aAddr);
        av[6] = ds_read_b128_imm<1536>(aAddr);
        av[7] = ds_read_b128_imm<1792>(aAddr);

        // wave-local: first 8 reads (av0-3, bv0-3) complete
        asm volatile("s_waitcnt lgkmcnt(4)" ::: "memory");
        __builtin_amdgcn_sched_barrier(0);
        __builtin_amdgcn_s_setprio(1);
#pragma unroll
        for (int mf = 0; mf < 4; ++mf)
#pragma unroll
            for (int nf = 0; nf < 4; ++nf)
                acc[mf][nf] = __builtin_amdgcn_mfma_f32_16x16x32_bf16(
                    av[mf], bv[nf], acc[mf][nf], 0, 0, 0);
        __builtin_amdgcn_s_setprio(0);

        asm volatile("s_waitcnt lgkmcnt(0)" ::: "memory");
        __builtin_amdgcn_sched_barrier(0);
        __builtin_amdgcn_s_setprio(1);
#pragma unroll
        for (int mf = 0; mf < 4; ++mf)
#pragma unroll
            for (int nf = 0; nf < 4; ++nf)
                acc[4 + mf][nf] = __builtin_amdgcn_mfma_f32_16x16x32_bf16(
                    av[4 + mf], bv[nf], acc[4 + mf][nf], 0, 0, 0);
        __builtin_amdgcn_s_setprio(0);
    }

    // epilogue: per-wave LDS transpose (stride 68 floats), coalesced stores.
    OutT* Cb = C + sC * bz + sSplit * sp;
    __syncthreads();   // all waves done with stage region before epi overlay
    float* lws = (float*)(smem_raw) + (size_t)w * 1088;
    const int lr = lane >> 4;
    const int lc = lane & 15;
#pragma unroll
    for (int mf = 0; mf < 8; ++mf) {
#pragma unroll
        for (int nf = 0; nf < 4; ++nf)
#pragma unroll
            for (int v = 0; v < 4; ++v)
                lws[(q * 4 + v) * 68 + nf * 16 + col] = acc[mf][nf][v];
#pragma unroll
        for (int p = 0; p < 4; ++p) {
            f32x4 t = *(const f32x4*)&lws[(p * 4 + lr) * 68 + lc * 4];
            int row  = tileM + wm * 128 + mf * 16 + p * 4 + lr;
            int colg = tileN + wn * 64 + lc * 4;
            if constexpr (sizeof(OutT) == 2) {
                u16x4 u;
                u[0] = f2bf(t[0]); u[1] = f2bf(t[1]);
                u[2] = f2bf(t[2]); u[3] = f2bf(t[3]);
                *(u16x4*)&Cb[(size_t)row * ldc + colg] = u;
            } else {
                *(f32x4*)&Cb[(size_t)row * ldc + colg] = t;
            }
        }
        // NOTE: per-wave epi slice is private; no barrier needed between mf
        // iterations (each wave reuses only its own 1088-float slice).
    }
}

extern "C" void kernel_launch(void* const* d_in, const int* in_sizes, int n_in,
                              void* d_out, int out_size, void* d_ws, size_t ws_size,
                              hipStream_t stream) {
    const float* X = (const float*)d_in[0];   // [4,4096,1024]
    const float* W = (const float*)d_in[1];   // [1024,1024]
    float* out = (float*)d_out;               // [4,4096,1024] fp32

    char* ws = (char*)d_ws;
    unsigned short* Xb = (unsigned short*)(ws);              // 33,554,432  [b][s][h]
    unsigned short* XT = (unsigned short*)(ws + 33554432);   // 33,554,432  [b][h][s]
    unsigned short* WT = (unsigned short*)(ws + 67108864);   //  2,097,152  [h'][o]
    unsigned short* G  = (unsigned short*)(ws + 69206016);   //  8,388,608  [b][o][h]
    unsigned short* MT = (unsigned short*)(ws + 77594624);   //  8,388,608  [b][h''][h]
    // Scratch (reused serially): Gpart then MTpart, each [sp(4)][b][1024][1024]
    unsigned short* Gpart  = (unsigned short*)(ws + 85983232); // 16,777,216
    unsigned short* MTpart = (unsigned short*)(ws + 85983232); // 16,777,216
    // high-water: 102,760,448 bytes < 153,092,096 proven available

    const size_t sBH = (size_t)B_DIM * H_DIM * H_DIM;

    // 1) casts + transposes
    cast_x_kernel<<<dim3(H_DIM / 64, S_DIM / 64, B_DIM), dim3(16, 16), 0, stream>>>(X, Xb, XT);
    cast_w_kernel<<<dim3(H_DIM / 32, H_DIM / 32, 1), dim3(32, 8), 0, stream>>>(W, WT);

    // 2) G_b = XT_b @ XT_b^T, full symmetric, split-K=4 (Ksub=1024, T=32).
    gemm_q4_kernel<unsigned short, 4><<<dim3(4, 4, B_DIM * 4), 512, 131072, stream>>>(
        XT, XT, Gpart, S_DIM, S_DIM, S_DIM, H_DIM,
        (size_t)H_DIM * S_DIM, (size_t)H_DIM * S_DIM, (size_t)H_DIM * H_DIM, sBH);
    reduce_cast_u16_kernel<4><<<dim3(sBH / 8 / 256), 256, 0, stream>>>(Gpart, G, sBH);

    // 3) MT_b = G_b @ WT^T, split-K=4 (Ksub=256, T=8)
    gemm_q4_kernel<unsigned short, 4><<<dim3(4, 4, B_DIM * 4), 512, 131072, stream>>>(
        G, WT, MTpart, H_DIM, H_DIM, H_DIM, H_DIM,
        (size_t)H_DIM * H_DIM, (size_t)0, (size_t)H_DIM * H_DIM, sBH);
    reduce_cast_u16_kernel<4><<<dim3(sBH / 8 / 256), 256, 0, stream>>>(MTpart, MT, sBH);

    // 4) att_b = Xb_b @ MT_b^T  [4096x1024], K=1024 (T=32), fp32 out.
    //    grid (16,4,4) = 256 blocks = 1/CU exactly.
    gemm_q4_kernel<float, 1><<<dim3(S_DIM / 256, H_DIM / 256, B_DIM), 512, 131072, stream>>>(
        Xb, MT, out, H_DIM, H_DIM, H_DIM, H_DIM,
        (size_t)S_DIM * H_DIM, (size_t)H_DIM * H_DIM, (size_t)S_DIM * H_DIM, 0);
}

// Round 5
// 258.507 us; speedup vs baseline: 1.1173x; 1.0147x over previous
//
#include <hip/hip_runtime.h>
#include <hip/hip_bf16.h>
#include <stdint.h>

#define H_DIM 1024
#define S_DIM 4096
#define B_DIM 4

typedef __bf16 bf16x8 __attribute__((ext_vector_type(8)));
typedef float f32x4 __attribute__((ext_vector_type(4)));
typedef unsigned short u16x4 __attribute__((ext_vector_type(4)));
typedef unsigned short u16x8 __attribute__((ext_vector_type(8)));

__device__ __forceinline__ unsigned short f2bf(float f) {
    union { float f; uint32_t u; } v; v.f = f;
    uint32_t u = v.u;
    uint32_t r = (u + 0x7FFFu + ((u >> 16) & 1u)) >> 16;  // round-to-nearest-even
    return (unsigned short)r;
}
__device__ __forceinline__ float bf2f(unsigned short u) {
    union { uint32_t u; float f; } v; v.u = (uint32_t)u << 16; return v.f;
}

// Raw barrier (no implicit vmcnt/lgkmcnt drain).
__device__ __forceinline__ void wg_barrier() {
    asm volatile("s_barrier" ::: "memory");
}

// Inline-asm LDS read: opaque to LDS-DMA alias tracking (compiler cannot
// insert vmcnt(0) drains). Ordering restored by gate+barrier BEFORE the read
// (DMA landing) and lgkmcnt(0)+sched_barrier(0) before the dependent MFMAs.
template <int IMM>
__device__ __forceinline__ bf16x8 ds_read_b128_imm(unsigned addr) {
    bf16x8 r;
    asm volatile("ds_read_b128 %0, %1 offset:%2"
                 : "=v"(r) : "v"(addr), "i"(IMM));
    return r;
}

// X[b][s][h] fp32 -> Xb[b][s][h] bf16  and  XT[b][h][s] bf16 (vectorized)
__global__ __launch_bounds__(256)
void cast_x_kernel(const float* __restrict__ X,
                   unsigned short* __restrict__ Xb,
                   unsigned short* __restrict__ XT) {
    __shared__ float tile[64][65];
    const int b  = blockIdx.z;
    const int h0 = blockIdx.x * 64;
    const int s0 = blockIdx.y * 64;
    const int tx = threadIdx.x;   // 0..15
    const int ty = threadIdx.y;   // 0..15
#pragma unroll
    for (int j = 0; j < 4; ++j) {
        int s = ty + 16 * j;
        f32x4 v = *(const f32x4*)&X[((size_t)b * S_DIM + s0 + s) * H_DIM + h0 + tx * 4];
        u16x4 o;
#pragma unroll
        for (int k = 0; k < 4; ++k) {
            tile[s][tx * 4 + k] = v[k];
            o[k] = f2bf(v[k]);
        }
        *(u16x4*)&Xb[((size_t)b * S_DIM + s0 + s) * H_DIM + h0 + tx * 4] = o;
    }
    __syncthreads();
#pragma unroll
    for (int j = 0; j < 4; ++j) {
        int hh = ty + 16 * j;
        u16x4 o;
#pragma unroll
        for (int k = 0; k < 4; ++k)
            o[k] = f2bf(tile[tx * 4 + k][hh]);
        *(u16x4*)&XT[((size_t)b * H_DIM + h0 + hh) * S_DIM + s0 + tx * 4] = o;
    }
}

// W[o][h'] fp32 -> WT[h'][o] bf16 (small: 4 MB read)
__global__ void cast_w_kernel(const float* __restrict__ W,
                              unsigned short* __restrict__ WT) {
    __shared__ float tile[32][33];
    const int b0 = blockIdx.x * 32;
    const int o0 = blockIdx.y * 32;
    const int tx = threadIdx.x;
    const int ty = threadIdx.y;
#pragma unroll
    for (int i = 0; i < 4; ++i) {
        int o = ty + 8 * i;
        tile[o][tx] = W[(size_t)(o0 + o) * H_DIM + b0 + tx];
    }
    __syncthreads();
#pragma unroll
    for (int i = 0; i < 4; ++i) {
        int bb = ty + 8 * i;
        WT[(size_t)(b0 + bb) * H_DIM + o0 + tx] = f2bf(tile[tx][bb]);
    }
}

// Sum NSPLIT bf16 partials -> bf16. 16B/lane both directions.
template <int NSPLIT>
__global__ void reduce_cast_u16_kernel(const unsigned short* __restrict__ P,
                                       unsigned short* __restrict__ Out,
                                       size_t sSplit) {
    size_t i = ((size_t)blockIdx.x * blockDim.x + threadIdx.x) * 8;
    float s[8] = {0.f, 0.f, 0.f, 0.f, 0.f, 0.f, 0.f, 0.f};
#pragma unroll
    for (int sp = 0; sp < NSPLIT; ++sp) {
        u16x8 u = *(const u16x8*)&P[(size_t)sp * sSplit + i];
#pragma unroll
        for (int k = 0; k < 8; ++k) s[k] += bf2f(u[k]);
    }
    u16x8 o;
#pragma unroll
    for (int k = 0; k < 8; ++k) o[k] = f2bf(s[k]);
    *(u16x8*)&Out[i] = o;
}

// ============================================================================
// R5: 4-phase paced GEMM, gate/read ordering FIXED (R4 raced: ds_reads were
// issued before the vmcnt gate + barrier that confirm the tile's DMA landed;
// vmcnt is per-wave and each wave stages only its own chunk, so the ONLY safe
// pattern is gate-own-loads -> s_barrier -> read).
//
// C[M,N] = A[M,K] @ Bt[N,K]^T  (bf16 in, fp32 accum, OutT out)
// Geometry: 256x256 tile, 512 threads = 8 waves (2M x 4N), wave-tile 128x64
// = 8x4 frags of v_mfma_f32_16x16x32_bf16. BK=64. LDS: 2 buffers x
// (A 32KB + B 32KB) = 131072 B, fragment-major [k8(8)][row(256)][8]
// (conflict-free ds_read_b128, linear global_load_lds dest).
// Half h of tile = k8 h*4..h*4+3 (kc=h), 16 KB per operand, 2 loads/thread.
//
// Per K-tile n (stages issue halves of tile n+1 into buf (n+1)&1):
//   G0: vmcnt(4) [own A(n,0),B(n,0) landed; A(n,1),B(n,1) in flight]; barrier
//   P0: 8 ds_reads kc0 | stage A(n+1,0) | lgkm(0)+schedbar | prio1 16MFMA prio0
//   P1: 4 ds_reads kc0-hi | stage B(n+1,0) | lgkm(0)+schedbar | prio1 16MFMA
//   G1: vmcnt(pf?4:0) [A(n,1),B(n,1) landed; n+1's first halves in flight];
//       barrier
//   P2: 8 ds_reads kc1 | stage A(n+1,1) | ... 16MFMA
//   P3: 4 ds_reads kc1-hi | stage B(n+1,1) | ... 16MFMA
// Gate math (2 loads/stage, issue order A0,B0,A1,B1 per tile): outstanding at
// every gate <= 8, needed = oldest 4 -> vmcnt(4) steady state; drains to 0
// only at the last tile's G1.
// WAR safety: restage of buf (n+1)&1 happens only after G0(n)/G1(n) barriers;
// every wave's tile-(n-1) reads of that buffer completed (data returned)
// before its own lgkmcnt(0), which precedes its barrier arrival.
// Works for any T >= 1. M,N multiples of 256.
// ============================================================================
template <typename OutT, int NSPLIT>
__global__ __launch_bounds__(512, 2)
void gemm_p5_kernel(const unsigned short* __restrict__ A,
                    const unsigned short* __restrict__ Bt,
                    OutT* __restrict__ C,
                    int K, int lda, int ldb, int ldc,
                    size_t sA, size_t sB, size_t sC, size_t sSplit) {
    extern __shared__ char smem_raw[];
    // stage: [buf(2)][A 32KB | B 32KB] = 131072 B; epi overlays post-sync.

    const int tid  = threadIdx.x;
    const int w    = tid >> 6;       // 0..7
    const int lane = tid & 63;
    const int wm   = w & 1;          // M half: rows wm*128
    const int wn   = w >> 1;         // N quarter: cols wn*64
    const int q    = lane >> 4;      // 0..3
    const int col  = lane & 15;

    const int tileM = blockIdx.x * 256;
    const int tileN = blockIdx.y * 256;
    const int bz   = blockIdx.z / NSPLIT;
    const int sp   = blockIdx.z % NSPLIT;
    const int Ksub = K / NSPLIT;
    const int T    = Ksub >> 6;      // K-tiles of 64

    const unsigned short* Ab = A + sA * bz + (size_t)sp * Ksub;
    const unsigned short* Bb = Bt + sB * bz + (size_t)sp * Ksub;

    auto lds3 = (__attribute__((address_space(3))) char*)&smem_raw[0];
    const unsigned ldsBase = (unsigned)(size_t)lds3;

    // fragment read bases (buf 0). A byte addr for (kc,mf):
    //   buf*65536 + kc*16384 + q*4096 + (wm*128 + mf*16 + col)*16
    //   -> imm = kc*16384 + mf*256 (max 18176, fits 16-bit offset)
    const unsigned aBase = ldsBase + (unsigned)(q * 4096 + (wm * 128 + col) * 16);
    const unsigned bBase = ldsBase + 32768u + (unsigned)(q * 4096 + (wn * 64 + col) * 16);

    // staging chunks: c = 2w+j -> k8rel = c>>2 (0..3), r64 = c&3; 1 KB/load.
    const unsigned short* pA[2];
    const unsigned short* pB[2];
    unsigned dstA[2];
#pragma unroll
    for (int j = 0; j < 2; ++j) {
        int c = 2 * w + j, k8r = c >> 2, r64 = c & 3;
        pA[j] = Ab + (size_t)(tileM + r64 * 64 + lane) * lda + k8r * 8;
        pB[j] = Bb + (size_t)(tileN + r64 * 64 + lane) * ldb + k8r * 8;
        dstA[j] = (unsigned)(k8r * 4096 + r64 * 1024);
    }
    // stage half h (kc=h) of A/B for target tile tgt into buf tgt&1
    auto stageA = [&](int tgt, int h) {
#pragma unroll
        for (int j = 0; j < 2; ++j)
            __builtin_amdgcn_global_load_lds(
                (const __attribute__((address_space(1))) void*)(pA[j] + tgt * 64 + h * 32),
                (__attribute__((address_space(3))) void*)(lds3 + ((unsigned)(tgt & 1) * 65536u + dstA[j] + (unsigned)h * 16384u)),
                16, 0, 0);
    };
    auto stageB = [&](int tgt, int h) {
#pragma unroll
        for (int j = 0; j < 2; ++j)
            __builtin_amdgcn_global_load_lds(
                (const __attribute__((address_space(1))) void*)(pB[j] + tgt * 64 + h * 32),
                (__attribute__((address_space(3))) void*)(lds3 + ((unsigned)(tgt & 1) * 65536u + 32768u + dstA[j] + (unsigned)h * 16384u)),
                16, 0, 0);
    };

    f32x4 acc[8][4];
#pragma unroll
    for (int r = 0; r < 8; ++r)
#pragma unroll
        for (int c = 0; c < 4; ++c)
            acc[r][c] = (f32x4){0.f, 0.f, 0.f, 0.f};

    // prologue: tile 0's 4 halves, consumption order A0,B0,A1,B1
    stageA(0, 0); stageB(0, 0); stageA(0, 1); stageB(0, 1);

    for (int n = 0; n < T; ++n) {
        const unsigned aAddr = aBase + (unsigned)((n & 1) << 16);
        const unsigned bAddr = bBase + (unsigned)((n & 1) << 16);
        const bool pf = (n + 1 < T);
        bf16x8 av[4], bv[4];

        // ===== G0: A(n,0),B(n,0) landed (own); barrier makes it collective =====
        asm volatile("s_waitcnt vmcnt(4)" ::: "memory");
        wg_barrier();

        // ---- P0: kc=0, mf 0..3 ----
        av[0] = ds_read_b128_imm<0>(aAddr);
        av[1] = ds_read_b128_imm<256>(aAddr);
        av[2] = ds_read_b128_imm<512>(aAddr);
        av[3] = ds_read_b128_imm<768>(aAddr);
        bv[0] = ds_read_b128_imm<0>(bAddr);
        bv[1] = ds_read_b128_imm<256>(bAddr);
        bv[2] = ds_read_b128_imm<512>(bAddr);
        bv[3] = ds_read_b128_imm<768>(bAddr);
        if (pf) stageA(n + 1, 0);
        asm volatile("s_waitcnt lgkmcnt(0)" ::: "memory");
        __builtin_amdgcn_sched_barrier(0);
        __builtin_amdgcn_s_setprio(1);
#pragma unroll
        for (int mf = 0; mf < 4; ++mf)
#pragma unroll
            for (int nf = 0; nf < 4; ++nf)
                acc[mf][nf] = __builtin_amdgcn_mfma_f32_16x16x32_bf16(
                    av[mf], bv[nf], acc[mf][nf], 0, 0, 0);
        __builtin_amdgcn_s_setprio(0);

        // ---- P1: kc=0, mf 4..7 (bv reused) ----
        av[0] = ds_read_b128_imm<1024>(aAddr);
        av[1] = ds_read_b128_imm<1280>(aAddr);
        av[2] = ds_read_b128_imm<1536>(aAddr);
        av[3] = ds_read_b128_imm<1792>(aAddr);
        if (pf) stageB(n + 1, 0);
        asm volatile("s_waitcnt lgkmcnt(0)" ::: "memory");
        __builtin_amdgcn_sched_barrier(0);
        __builtin_amdgcn_s_setprio(1);
#pragma unroll
        for (int mf = 0; mf < 4; ++mf)
#pragma unroll
            for (int nf = 0; nf < 4; ++nf)
                acc[4 + mf][nf] = __builtin_amdgcn_mfma_f32_16x16x32_bf16(
                    av[mf], bv[nf], acc[4 + mf][nf], 0, 0, 0);
        __builtin_amdgcn_s_setprio(0);

        // ===== G1: A(n,1),B(n,1) landed; n+1's first halves stay in flight =====
        if (pf) asm volatile("s_waitcnt vmcnt(4)" ::: "memory");
        else    asm volatile("s_waitcnt vmcnt(0)" ::: "memory");
        wg_barrier();

        // ---- P2: kc=1, mf 0..3, new bv ----
        av[0] = ds_read_b128_imm<16384 + 0>(aAddr);
        av[1] = ds_read_b128_imm<16384 + 256>(aAddr);
        av[2] = ds_read_b128_imm<16384 + 512>(aAddr);
        av[3] = ds_read_b128_imm<16384 + 768>(aAddr);
        bv[0] = ds_read_b128_imm<16384 + 0>(bAddr);
        bv[1] = ds_read_b128_imm<16384 + 256>(bAddr);
        bv[2] = ds_read_b128_imm<16384 + 512>(bAddr);
        bv[3] = ds_read_b128_imm<16384 + 768>(bAddr);
        if (pf) stageA(n + 1, 1);
        asm volatile("s_waitcnt lgkmcnt(0)" ::: "memory");
        __builtin_amdgcn_sched_barrier(0);
        __builtin_amdgcn_s_setprio(1);
#pragma unroll
        for (int mf = 0; mf < 4; ++mf)
#pragma unroll
            for (int nf = 0; nf < 4; ++nf)
                acc[mf][nf] = __builtin_amdgcn_mfma_f32_16x16x32_bf16(
                    av[mf], bv[nf], acc[mf][nf], 0, 0, 0);
        __builtin_amdgcn_s_setprio(0);

        // ---- P3: kc=1, mf 4..7 ----
        av[0] = ds_read_b128_imm<16384 + 1024>(aAddr);
        av[1] = ds_read_b128_imm<16384 + 1280>(aAddr);
        av[2] = ds_read_b128_imm<16384 + 1536>(aAddr);
        av[3] = ds_read_b128_imm<16384 + 1792>(aAddr);
        if (pf) stageB(n + 1, 1);
        asm volatile("s_waitcnt lgkmcnt(0)" ::: "memory");
        __builtin_amdgcn_sched_barrier(0);
        __builtin_amdgcn_s_setprio(1);
#pragma unroll
        for (int mf = 0; mf < 4; ++mf)
#pragma unroll
            for (int nf = 0; nf < 4; ++nf)
                acc[4 + mf][nf] = __builtin_amdgcn_mfma_f32_16x16x32_bf16(
                    av[mf], bv[nf], acc[4 + mf][nf], 0, 0, 0);
        __builtin_amdgcn_s_setprio(0);
    }

    // epilogue: per-wave LDS transpose (stride 68 floats), coalesced stores.
    OutT* Cb = C + sC * bz + sSplit * sp;
    __syncthreads();   // all waves done with stage region before epi overlay
    float* lws = (float*)(smem_raw) + (size_t)w * 1088;
    const int lr = lane >> 4;
    const int lc = lane & 15;
#pragma unroll
    for (int mf = 0; mf < 8; ++mf) {
#pragma unroll
        for (int nf = 0; nf < 4; ++nf)
#pragma unroll
            for (int v = 0; v < 4; ++v)
                lws[(q * 4 + v) * 68 + nf * 16 + col] = acc[mf][nf][v];
#pragma unroll
        for (int p = 0; p < 4; ++p) {
            f32x4 t = *(const f32x4*)&lws[(p * 4 + lr) * 68 + lc * 4];
            int row  = tileM + wm * 128 + mf * 16 + p * 4 + lr;
            int colg = tileN + wn * 64 + lc * 4;
            if constexpr (sizeof(OutT) == 2) {
                u16x4 u;
                u[0] = f2bf(t[0]); u[1] = f2bf(t[1]);
                u[2] = f2bf(t[2]); u[3] = f2bf(t[3]);
                *(u16x4*)&Cb[(size_t)row * ldc + colg] = u;
            } else {
                *(f32x4*)&Cb[(size_t)row * ldc + colg] = t;
            }
        }
        // per-wave epi slice is private; no inter-mf barrier needed
    }
}

extern "C" void kernel_launch(void* const* d_in, const int* in_sizes, int n_in,
                              void* d_out, int out_size, void* d_ws, size_t ws_size,
                              hipStream_t stream) {
    const float* X = (const float*)d_in[0];   // [4,4096,1024]
    const float* W = (const float*)d_in[1];   // [1024,1024]
    float* out = (float*)d_out;               // [4,4096,1024] fp32

    char* ws = (char*)d_ws;
    unsigned short* Xb = (unsigned short*)(ws);              // 33,554,432  [b][s][h]
    unsigned short* XT = (unsigned short*)(ws + 33554432);   // 33,554,432  [b][h][s]
    unsigned short* WT = (unsigned short*)(ws + 67108864);   //  2,097,152  [h'][o]
    unsigned short* G  = (unsigned short*)(ws + 69206016);   //  8,388,608  [b][o][h]
    unsigned short* MT = (unsigned short*)(ws + 77594624);   //  8,388,608  [b][h''][h]
    // Scratch (reused serially): Gpart then MTpart, each [sp(4)][b][1024][1024]
    unsigned short* Gpart  = (unsigned short*)(ws + 85983232); // 16,777,216
    unsigned short* MTpart = (unsigned short*)(ws + 85983232); // 16,777,216
    // high-water: 102,760,448 bytes < 153,092,096 proven available

    const size_t sBH = (size_t)B_DIM * H_DIM * H_DIM;

    // 1) casts + transposes
    cast_x_kernel<<<dim3(H_DIM / 64, S_DIM / 64, B_DIM), dim3(16, 16), 0, stream>>>(X, Xb, XT);
    cast_w_kernel<<<dim3(H_DIM / 32, H_DIM / 32, 1), dim3(32, 8), 0, stream>>>(W, WT);

    // 2) G_b = XT_b @ XT_b^T, full symmetric, split-K=4 (Ksub=1024, T=16).
    gemm_p5_kernel<unsigned short, 4><<<dim3(4, 4, B_DIM * 4), 512, 131072, stream>>>(
        XT, XT, Gpart, S_DIM, S_DIM, S_DIM, H_DIM,
        (size_t)H_DIM * S_DIM, (size_t)H_DIM * S_DIM, (size_t)H_DIM * H_DIM, sBH);
    reduce_cast_u16_kernel<4><<<dim3(sBH / 8 / 256), 256, 0, stream>>>(Gpart, G, sBH);

    // 3) MT_b = G_b @ WT^T, split-K=4 (Ksub=256, T=4)
    gemm_p5_kernel<unsigned short, 4><<<dim3(4, 4, B_DIM * 4), 512, 131072, stream>>>(
        G, WT, MTpart, H_DIM, H_DIM, H_DIM, H_DIM,
        (size_t)H_DIM * H_DIM, (size_t)0, (size_t)H_DIM * H_DIM, sBH);
    reduce_cast_u16_kernel<4><<<dim3(sBH / 8 / 256), 256, 0, stream>>>(MTpart, MT, sBH);

    // 4) att_b = Xb_b @ MT_b^T  [4096x1024], K=1024 (T=16), fp32 out.
    //    grid (16,4,4) = 256 blocks = 1/CU exactly.
    gemm_p5_kernel<float, 1><<<dim3(S_DIM / 256, H_DIM / 256, B_DIM), 512, 131072, stream>>>(
        Xb, MT, out, H_DIM, H_DIM, H_DIM, H_DIM,
        (size_t)S_DIM * H_DIM, (size_t)H_DIM * H_DIM, (size_t)S_DIM * H_DIM, 0);
}